// Round 1
// baseline (225.058 us; speedup 1.0000x reference)
//
#include <hip/hip_runtime.h>
#include <stdint.h>

// ExactTopKAttention: B=1, T=S=2048, H=16, E=64, topk=32, fp32.
//
// R13: GEMM issue-efficiency. R12 counters: VALUBusy 74.5% x 166us = 124us
// of VALU issue vs a ~46-55us model floor (1024 v_pk_fma_f32/wave = 27us
// chip-wide + ~19us phases). Suspected gap: LLVM materializes the Q-splat
// {q,q} as v_mov pairs instead of encoding the broadcast via VOP3P op_sel
// on the scalar-loaded SGPR pair. Change: inline-asm v_pk_fma_f32 with
//   op_sel:[0,0,0] op_sel_hi:[0,1,1]  -> splat q.x (low dword of sgpr pair)
//   op_sel:[1,0,0] op_sel_hi:[1,1,1]  -> splat q.y (high dword)
// consuming the s_load_dwordx2 result directly (1 SGPR operand per instr,
// legal). Bit-exact: same IEEE fma, identical accumulation order as R12.
// Everything else (LDS layout, threshold, collect, sort, softmax, V) is
// byte-identical to R12.
//
// Carried invariants (R8-R12):
//   kernel 1: transpose K per head -> KT[h][e][s] in d_ws (8 MB).
//   kernel 2: block = (h, 8 t-rows), 512 thr = 8 waves; wave owns a 256-wide
//     s-slice of all 8 rows; acc2[8][2] v2f = 32 VGPRs; per e-pair 2
//     coalesced float4 KT loads (L2-resident per head; bx&15=h pins same-h
//     blocks to one XCD) + Q uniform scalar loads; no LDS in the GEMM.
//   Bit-exact scores: sequential fma chain over e=0..63 per (t,s);
//     *0.125f applied at decode (exact pow2).
//   LDS scores as u16 = ord32>>16 (32 KB); threshold on 16-bit domain;
//     candidates collected with EXACT u32 values from accumulator regs;
//     37.4 KB LDS -> 4 blocks/CU.
//   Exact top-32: 64-wide bitonic on ((ord32<<32)|~idx) = value desc, index
//     asc (lax.top_k tie order); softmax over 32; V gather; store.

#define T_DIM 2048
#define S_DIM 2048
#define H_DIM 16
#define E_DIM 64
#define K_TOP 32
#define TT 8         // t rows per block
#define NWAVE 8

typedef float v2f __attribute__((ext_vector_type(2)));
typedef float v4f __attribute__((ext_vector_type(4)));

// acc = {q.x,q.x} * k + acc   (q is a uniform sgpr pair; op_sel splats lo dword)
__device__ __forceinline__ void pk_fma_slo(v2f& acc, v2f q, v2f k) {
    asm("v_pk_fma_f32 %0, %1, %2, %0 op_sel:[0,0,0] op_sel_hi:[0,1,1]"
        : "+v"(acc) : "s"(q), "v"(k));
}
// acc = {q.y,q.y} * k + acc   (op_sel splats hi dword of the sgpr pair)
__device__ __forceinline__ void pk_fma_shi(v2f& acc, v2f q, v2f k) {
    asm("v_pk_fma_f32 %0, %1, %2, %0 op_sel:[1,0,0] op_sel_hi:[1,1,1]"
        : "+v"(acc) : "s"(q), "v"(k));
}

// order-preserving float->uint map (monotone increasing)
__device__ __forceinline__ unsigned f2ord(float f) {
    unsigned b = __float_as_uint(f);
    return (b & 0x80000000u) ? ~b : (b | 0x80000000u);
}
__device__ __forceinline__ float ord2f(unsigned u) {
    unsigned b = (u & 0x80000000u) ? (u ^ 0x80000000u) : ~u;
    return __uint_as_float(b);
}

// ---- kernel 1: K[s][h][e] -> KT[h][e][s] ----
__global__ __launch_bounds__(256)
void transpose_k(const float* __restrict__ Kg, float* __restrict__ KT) {
    __shared__ float tile[64][65];
    const int tid = threadIdx.x;
    const int h   = blockIdx.x & (H_DIM - 1);
    const int sb  = (blockIdx.x >> 4) * 64;
    #pragma unroll
    for (int sw = 0; sw < 4; sw++) {            // read 64s x 64e, coalesced on e
        int r = sw * 16 + (tid >> 4);
        int c = (tid & 15) * 4;
        float4 v = *(const float4*)(Kg + ((size_t)(sb + r) * H_DIM + h) * E_DIM + c);
        tile[r][c] = v.x; tile[r][c+1] = v.y; tile[r][c+2] = v.z; tile[r][c+3] = v.w;
    }
    __syncthreads();
    #pragma unroll
    for (int sw = 0; sw < 4; sw++) {            // write coalesced on s
        int e = sw * 16 + (tid >> 4);
        int j = (tid & 15) * 4;
        float4 v = { tile[j][e], tile[j+1][e], tile[j+2][e], tile[j+3][e] };
        *(float4*)(KT + ((size_t)h * E_DIM + e) * S_DIM + sb + j) = v;
    }
}

// ---- kernel 2: fused GEMM + exact top-32 + softmax + V ----
__global__ __launch_bounds__(512, 2)
void topk_attn_kernel(const float* __restrict__ Qg,
                      const float* __restrict__ KT,
                      const float* __restrict__ Vg,
                      float* __restrict__ Out) {
    __shared__ __align__(16) unsigned short sU[TT][S_DIM];  // 32 KB u16 keys
    __shared__ unsigned candU[TT][64];
    __shared__ int      candI[TT][64];
    __shared__ unsigned wcnt[TT];
    __shared__ unsigned thrA[TT];

    const int tid  = threadIdx.x;
    const int lane = tid & 63;
    const int wv   = tid >> 6;                 // wave 0..7
    const int bx   = blockIdx.x;
    const int h    = bx & (H_DIM - 1);         // same-h blocks -> same XCD
    const int tb   = bx >> 4;
    const int t0   = tb * TT;                  // block's first t row

    // ---- GEMM: acc2[t] = two v2f over this wave's 4 consecutive s ----
    v2f acc2[TT][2];
    #pragma unroll
    for (int t = 0; t < TT; t++) { acc2[t][0] = (v2f)(0.f); acc2[t][1] = (v2f)(0.f); }

    const int   sb  = wv * 256 + (lane << 2);  // first s of this lane
    const float* kp = KT + (size_t)h * E_DIM * S_DIM + sb;
    const float* Qb = Qg + ((size_t)t0 * H_DIM + h) * E_DIM;  // row stride 1024

    v4f k0q = *(const v4f*)(kp);
    v4f k1q = *(const v4f*)(kp + S_DIM);
    for (int e2 = 0; e2 < 32; e2++) {
        const int ep = (e2 + 1) & 31;          // wraps to 0 on last iter (harmless)
        v4f n0q = *(const v4f*)(kp + (size_t)(2 * ep)     * S_DIM);
        v4f n1q = *(const v4f*)(kp + (size_t)(2 * ep + 1) * S_DIM);
        v2f k0lo = __builtin_shufflevector(k0q, k0q, 0, 1);
        v2f k0hi = __builtin_shufflevector(k0q, k0q, 2, 3);
        v2f k1lo = __builtin_shufflevector(k1q, k1q, 0, 1);
        v2f k1hi = __builtin_shufflevector(k1q, k1q, 2, 3);
        #pragma unroll
        for (int t = 0; t < TT; t++) {
            // uniform address (blockIdx/loop-derived only) -> s_load_dwordx2;
            // the resulting sgpr pair feeds v_pk_fma_f32 via op_sel splat.
            v2f qv = *(const v2f*)(Qb + (size_t)t * (H_DIM * E_DIM) + 2 * e2);
            pk_fma_slo(acc2[t][0], qv, k0lo);   // e even
            pk_fma_slo(acc2[t][1], qv, k0hi);
            pk_fma_shi(acc2[t][0], qv, k1lo);   // e odd
            pk_fma_shi(acc2[t][1], qv, k1hi);
        }
        k0q = n0q; k1q = n1q;
    }

    // ---- write u16 ordered keys to LDS (acc2 stays live for collect) ----
    #pragma unroll
    for (int r = 0; r < TT; r++) {
        unsigned a = f2ord(acc2[r][0].x) >> 16;
        unsigned b = f2ord(acc2[r][0].y) >> 16;
        unsigned c = f2ord(acc2[r][1].x) >> 16;
        unsigned d = f2ord(acc2[r][1].y) >> 16;
        uint2 pk; pk.x = a | (b << 16); pk.y = c | (d << 16);
        *(uint2*)(&sU[r][sb]) = pk;
    }
    if (lane == 0) wcnt[wv] = 0u;
    __syncthreads();

    // ---- threshold find: wave wv owns row wv, 16-bit domain ----
    unsigned pk16[16];                         // packed u16 pairs of row wv
    {
        const unsigned* rowp = (const unsigned*)(&sU[wv][0]);
        #pragma unroll
        for (int j = 0; j < 16; j++) pk16[j] = rowp[j * 64 + lane];
    }
    auto count16 = [&](unsigned t) -> int {    // wave-uniform result
        int c = 0;
        #pragma unroll
        for (int j = 0; j < 16; j++) {
            c += __popcll(__ballot((pk16[j] & 0xFFFFu) >= t));
            c += __popcll(__ballot((pk16[j] >> 16) >= t));
        }
        return c;
    };

    unsigned thr = 0xC180u;                    // f2ord(16.0f)>>16 (2sigma)
    int c = count16(thr);
    if (c < K_TOP || c > 64) {                 // ~2% of rows
        // invariant: count(lo) >= 32 (count(0)=2048), count(hi) < 32
        unsigned lo = (c >= K_TOP) ? thr : 0u;
        unsigned hi = (c >= K_TOP) ? 0x10000u : thr;
        bool found = false;
        while (!found && (hi - lo > 1u)) {
            unsigned mid = lo + ((hi - lo) >> 1);
            int cm = count16(mid);
            if (cm >= K_TOP && cm <= 64) { thr = mid; c = cm; found = true; }
            else if (cm >= K_TOP) lo = mid;
            else hi = mid;
        }
        if (!found) { thr = lo; c = count16(lo); }  // bin-tie clamp (rare)
    }
    if (lane == 0) thrA[wv] = thr;
    __syncthreads();

    // ---- collect: every wave appends its register-exact candidates ----
    #pragma unroll
    for (int r = 0; r < TT; r++) {
        unsigned tr = thrA[r];                 // same-address broadcast read
        unsigned uu0 = f2ord(acc2[r][0].x);
        unsigned uu1 = f2ord(acc2[r][0].y);
        unsigned uu2 = f2ord(acc2[r][1].x);
        unsigned uu3 = f2ord(acc2[r][1].y);
        unsigned uu[4] = {uu0, uu1, uu2, uu3};
        #pragma unroll
        for (int q = 0; q < 4; q++) {
            if ((uu[q] >> 16) >= tr) {
                unsigned pos = atomicAdd(&wcnt[r], 1u);
                if (pos < 64u) {
                    candU[r][pos] = uu[q];
                    candI[r][pos] = sb + q;
                }
            }
        }
    }
    __syncthreads();

    // ---- wave wv: bitonic + softmax + V gather for row wv ----
    unsigned nw = wcnt[wv];
    int n = (nw > 64u) ? 64 : (int)nw;         // pathological-tie clamp

    unsigned long long key = 0ull;
    if (lane < n)
        key = (((unsigned long long)candU[wv][lane]) << 32)
            | (unsigned)(~candI[wv][lane]);
    #pragma unroll
    for (int k = 2; k <= 64; k <<= 1)
        #pragma unroll
        for (int j = k >> 1; j > 0; j >>= 1) {
            unsigned long long ok = __shfl_xor(key, j);
            bool takemax = ((lane & j) == 0) ^ ((lane & k) != 0);
            bool mineG   = key > ok;
            key = (takemax == mineG) ? key : ok;
        }

    // --- decode (apply exact pow2 scale now), softmax, V gather, store ---
    const float* Vb = Vg + (size_t)h * E_DIM;
    float val  = ord2f((unsigned)(key >> 32)) * 0.125f;
    int   sidx = (int)(~(unsigned)key);
    float m = __shfl(val, 0);                  // lane 0 = max (n >= 32 always)
    float w = (lane < K_TOP) ? expf(val - m) : 0.f;
    float Z = w;
    #pragma unroll
    for (int d = 32; d > 0; d >>= 1) Z += __shfl_xor(Z, d);
    float pr = w / Z;

    float o = 0.f;
    #pragma unroll
    for (int i2 = 0; i2 < K_TOP; i2++) {
        float pi = __shfl(pr, i2);
        int   s2 = __shfl(sidx, i2);
        o = fmaf(pi, Vb[(size_t)s2 * (H_DIM * E_DIM) + lane], o);
    }
    int t = t0 + wv;
    Out[((size_t)t * H_DIM + h) * E_DIM + lane] = o;
}

extern "C" void kernel_launch(void* const* d_in, const int* in_sizes, int n_in,
                              void* d_out, int out_size, void* d_ws, size_t ws_size,
                              hipStream_t stream) {
    const float* Q = (const float*)d_in[0];
    const float* K = (const float*)d_in[1];
    const float* V = (const float*)d_in[2];
    float* O  = (float*)d_out;
    float* KT = (float*)d_ws;                  // 16*64*2048*4 = 8 MB
    (void)in_sizes; (void)n_in; (void)out_size; (void)ws_size;
    transpose_k<<<dim3(H_DIM * (S_DIM / 64)), dim3(256), 0, stream>>>(K, KT);
    topk_attn_kernel<<<dim3((T_DIM / TT) * H_DIM), dim3(512), 0, stream>>>(Q, KT, V, O);
}